// Round 1
// baseline (80.640 us; speedup 1.0000x reference)
//
#include <hip/hip_runtime.h>
#include <math.h>

#define NPAIR 31
#define BATCH 32768

typedef float f32x4 __attribute__((ext_vector_type(4)));
typedef int   i32x8 __attribute__((ext_vector_type(8)));
typedef unsigned int u32x2 __attribute__((ext_vector_type(2)));
typedef unsigned int u32x4 __attribute__((ext_vector_type(4)));

// pack 4 fp32 -> dword of 4 fp8 e4m3 (bytes 0..3 = a,b,c,d)
__device__ __forceinline__ unsigned pack_fp8x4(float a, float b, float c, float d) {
    int r = __builtin_amdgcn_cvt_pk_fp8_f32(a, b, 0, false);
    r = __builtin_amdgcn_cvt_pk_fp8_f32(c, d, r, true);
    return (unsigned)r;
}

// Pair swaps across 16-lane rows / 32-lane halves (gfx950 VALU permlane ops).
// lane_swap16(a) -> ev = value of even row of the row-pair, od = odd row's value
// lane_swap16: vdst.row1<->vsrc.row0, vdst.row3<->vsrc.row2 with both srcs = a
__device__ __forceinline__ void lane_swap16(unsigned a, unsigned& ev, unsigned& od) {
#if __has_builtin(__builtin_amdgcn_permlane16_swap)
    auto r = __builtin_amdgcn_permlane16_swap((int)a, (int)a, false, false);
    ev = (unsigned)r[0]; od = (unsigned)r[1];
#else
    unsigned p = (unsigned)__shfl_xor((int)a, 16);
    bool hi = (threadIdx.x >> 4) & 1;
    ev = hi ? p : a; od = hi ? a : p;
#endif
}
// lane_swap32(a) -> lo = lower-32-lane value, hi = upper-32-lane value
__device__ __forceinline__ void lane_swap32(unsigned a, unsigned& lo, unsigned& hi) {
#if __has_builtin(__builtin_amdgcn_permlane32_swap)
    auto r = __builtin_amdgcn_permlane32_swap((int)a, (int)a, false, false);
    lo = (unsigned)r[0]; hi = (unsigned)r[1];
#else
    unsigned p = (unsigned)__shfl_xor((int)a, 32);
    bool up = (threadIdx.x & 32) != 0;
    lo = up ? p : a; hi = up ? a : p;
#endif
}

// ---- Prefix: site-pair products T[2i][v0]*T[2i+1][v1] as fp8 MX-A rows -----
// Block = (pair i)*4 + variant v. Same math as before (o[jj] = P[lam(8h+jj)]),
// but stored in the 16x16x128 f8f6f4 A-operand layout: lane (q,m) of the main
// kernel holds row m, K-block q (= variant q), bytes j=0..31, value
// P_q[lam(j), 16t+m]. ws dword addr = (((i*4+v)*2 + t)*16 + m)*8 + h*2 + dd.
__global__ __launch_bounds__(64) void prefix_kernel(const float* __restrict__ t_mid,
                                                    unsigned* __restrict__ wsP) {
    __shared__ float M1s[1024], M2s[1024];
    const int l = threadIdx.x, h = l >> 4, m = l & 15;
    const int i = blockIdx.x >> 2, v = blockIdx.x & 3;

    const float4* s1 = (const float4*)(t_mid + (size_t)((2 * i) * 2 + (v & 1)) * 1024);
    const float4* s2 = (const float4*)(t_mid + (size_t)((2 * i + 1) * 2 + (v >> 1)) * 1024);
    #pragma unroll
    for (int c = 0; c < 4; ++c) {
        ((float4*)M1s)[c * 64 + l] = s1[c * 64 + l];
        ((float4*)M2s)[c * 64 + l] = s2[c * 64 + l];
    }
    __syncthreads();

    // cache this lane's two output columns of M2
    float colv[2][32];
    #pragma unroll
    for (int t = 0; t < 2; ++t)
        #pragma unroll
        for (int mm = 0; mm < 32; ++mm)
            colv[t][mm] = M2s[mm * 32 + 16 * t + m];

    float o0[8], o1[8];  // tile0/tile1, byte jj of this lane's h-block
    #pragma unroll
    for (int j = 0; j < 8; ++j) {
        int a = 16 * (j >> 2) + 4 * h + (j & 3);  // lam(8h+j)
        float acc0 = 0.f, acc1 = 0.f;
        #pragma unroll
        for (int mm = 0; mm < 32; ++mm) {
            float r = M1s[a * 32 + mm];
            acc0 = fmaf(r, colv[0][mm], acc0);
            acc1 = fmaf(r, colv[1][mm], acc1);
        }
        o0[j] = acc0;
        o1[j] = acc1;
    }

    unsigned* dst0 = wsP + (((size_t)blockIdx.x * 2 + 0) * 16 + m) * 8 + h * 2;
    u32x2 w0 = {pack_fp8x4(o0[0], o0[1], o0[2], o0[3]),
                pack_fp8x4(o0[4], o0[5], o0[6], o0[7])};
    *(u32x2*)dst0 = w0;
    unsigned* dst1 = wsP + (((size_t)blockIdx.x * 2 + 1) * 16 + m) * 8 + h * 2;
    u32x2 w1 = {pack_fp8x4(o1[0], o1[1], o1[2], o1[3]),
                pack_fp8x4(o1[4], o1[5], o1[6], o1[7])};
    *(u32x2*)dst1 = w1;
}

// ---------------------------- Main MFMA kernel -----------------------------
// One wave = 16 batch elements (element = lane&15). Per pair-step: gather the
// element's full 32-component fp8 state across its 4 q-lanes (6 permlane
// swaps), mask to the variant block (q == 2 spin bits), then a SINGLE
// mfma_scale 16x16x128 per output tile (K = 4 variants x 32 bond, unit
// scales). pow2 rescale every step (exact log bookkeeping), repack to fp8.
#define MPS_STEP(QQ, PF) do {                                                 \
    unsigned vl = (unsigned)mrot & 3u; mrot >>= 2;                            \
    unsigned E0, O0, E1, O1;                                                  \
    lane_swap16(Bd0, E0, O0); lane_swap16(Bd1, E1, O1);                       \
    unsigned g0, g1, g2, g3, g4, g5, g6, g7;                                  \
    lane_swap32(E0, g0, g4); lane_swap32(E1, g1, g5);                         \
    lane_swap32(O0, g2, g6); lane_swap32(O1, g3, g7);                         \
    bool selq = (vl == (unsigned)q);                                          \
    i32x8 Bv;                                                                 \
    Bv[0] = selq ? (int)g0 : 0; Bv[1] = selq ? (int)g1 : 0;                   \
    Bv[2] = selq ? (int)g2 : 0; Bv[3] = selq ? (int)g3 : 0;                   \
    Bv[4] = selq ? (int)g4 : 0; Bv[5] = selq ? (int)g5 : 0;                   \
    Bv[6] = selq ? (int)g6 : 0; Bv[7] = selq ? (int)g7 : 0;                   \
    i32x8 A0v, A1v;                                                           \
    A0v[0]=(int)QQ[0][0]; A0v[1]=(int)QQ[0][1]; A0v[2]=(int)QQ[0][2]; A0v[3]=(int)QQ[0][3]; \
    A0v[4]=(int)QQ[1][0]; A0v[5]=(int)QQ[1][1]; A0v[6]=(int)QQ[1][2]; A0v[7]=(int)QQ[1][3]; \
    A1v[0]=(int)QQ[2][0]; A1v[1]=(int)QQ[2][1]; A1v[2]=(int)QQ[2][2]; A1v[3]=(int)QQ[2][3]; \
    A1v[4]=(int)QQ[3][0]; A1v[5]=(int)QQ[3][1]; A1v[6]=(int)QQ[3][2]; A1v[7]=(int)QQ[3][3]; \
    const u32x4* pf_ = (PF);                                                  \
    if (pf_) { QQ[0] = pf_[0]; QQ[1] = pf_[1]; QQ[2] = pf_[32]; QQ[3] = pf_[33]; } \
    f32x4 y0 = __builtin_amdgcn_mfma_scale_f32_16x16x128_f8f6f4(              \
        A0v, Bv, cz, 0, 0, 0, 0x7f7f7f7f, 0, 0x7f7f7f7f);                     \
    f32x4 y1 = __builtin_amdgcn_mfma_scale_f32_16x16x128_f8f6f4(              \
        A1v, Bv, cz, 0, 0, 0, 0x7f7f7f7f, 0, 0x7f7f7f7f);                     \
    _Pragma("unroll")                                                         \
    for (int r = 0; r < 4; ++r) { st[r] = y0[r]; st[4 + r] = y1[r]; }         \
    float mx = fmaxf(fmaxf(fmaxf(st[0], st[1]), fmaxf(st[2], st[3])),         \
                     fmaxf(fmaxf(st[4], st[5]), fmaxf(st[6], st[7])));        \
    { unsigned a_, b_;                                                        \
      lane_swap16(__float_as_uint(mx), a_, b_);                               \
      mx = fmaxf(__uint_as_float(a_), __uint_as_float(b_));                   \
      lane_swap32(__float_as_uint(mx), a_, b_);                               \
      mx = fmaxf(__uint_as_float(a_), __uint_as_float(b_)); }                 \
    int ex = (int)((__float_as_uint(mx) >> 23) & 0xFF) - 127;                 \
    float sc = __uint_as_float((unsigned)(127 - ex) << 23);                   \
    _Pragma("unroll")                                                         \
    for (int j = 0; j < 8; ++j) st[j] *= sc;                                  \
    expsum += ex;                                                             \
    Bd0 = pack_fp8x4(st[0], st[1], st[2], st[3]);                             \
    Bd1 = pack_fp8x4(st[4], st[5], st[6], st[7]);                             \
} while (0)

__global__ __launch_bounds__(256, 2) void mps_mfma_kernel(
    const float* __restrict__ t_first,
    const float* __restrict__ t_last,
    const int*   __restrict__ x,
    const unsigned* __restrict__ wsP,
    float* __restrict__ out)
{
    const int tid  = threadIdx.x;
    const int w    = tid >> 6;
    const int l    = tid & 63;
    const int q    = l >> 4;
    const int e    = l & 15;
    const int base = (blockIdx.x * 4 + w) * 16;

    // ---- Inline spin mask for element e: bit s = (x[base+e][s] > 0). ----
    unsigned long long mrot;
    {
        const int4* xr = (const int4*)(x + (size_t)(base + e) * 64 + 16 * q);
        unsigned chunk = 0;
        #pragma unroll
        for (int c = 0; c < 4; ++c) {
            int4 vv = xr[c];
            chunk |= (unsigned)(vv.x > 0) << (4 * c + 0);
            chunk |= (unsigned)(vv.y > 0) << (4 * c + 1);
            chunk |= (unsigned)(vv.z > 0) << (4 * c + 2);
            chunk |= (unsigned)(vv.w > 0) << (4 * c + 3);
        }
        unsigned sh = chunk << ((q & 1) * 16);
        unsigned lo = (q < 2) ? sh : 0u;
        unsigned hi = (q >= 2) ? sh : 0u;
        lo |= (unsigned)__shfl_xor((int)lo, 16);
        lo |= (unsigned)__shfl_xor((int)lo, 32);
        hi |= (unsigned)__shfl_xor((int)hi, 16);
        hi |= (unsigned)__shfl_xor((int)hi, 32);
        unsigned long long mask = ((unsigned long long)hi << 32) | lo;
        // init below uses bit0; pairs consume bits 1..62; bit63 = t_last
        mrot = mask >> 1;
    }

    // ---- Init state (lam component order) from t_first[bit0]. ----
    float st[8];
    {
        const float* tf = t_first + ((x[(size_t)(base + e) * 64] > 0) ? 32 : 0);
        #pragma unroll
        for (int j = 0; j < 8; ++j)
            st[j] = tf[16 * (j >> 2) + 4 * q + (j & 3)];
    }
    unsigned Bd0 = pack_fp8x4(st[0], st[1], st[2], st[3]);
    unsigned Bd1 = pack_fp8x4(st[4], st[5], st[6], st[7]);

    int expsum = 0;
    const f32x4 cz = {0.f, 0.f, 0.f, 0.f};

    // Per step s, this lane's A rows: tile0 at Wl[s*256 + {0,1}],
    // tile1 at Wl[s*256 + {32,33}] (u32x4 units). 2-step rolling prefetch.
    const u32x4* Wl = (const u32x4*)wsP + (q * 64 + e * 2);
    u32x4 Q0[4], Q1[4];
    Q0[0] = Wl[0];   Q0[1] = Wl[1];   Q0[2] = Wl[32];  Q0[3] = Wl[33];
    Q1[0] = Wl[256]; Q1[1] = Wl[257]; Q1[2] = Wl[288]; Q1[3] = Wl[289];

    const u32x4* pf = Wl + 512;  // step-2 frags
    for (int k = 0; k < 15; ++k) {
        MPS_STEP(Q0, pf);                                        // step 2k
        MPS_STEP(Q1, (k < 14) ? (pf + 256) : (const u32x4*)0);   // step 2k+1
        pf += 512;
    }
    MPS_STEP(Q0, (const u32x4*)0);  // step 30

    // ---- Epilogue: amp = dot(state, t_last[bit63]); reduce over q. ----
    const float* tl = t_last + ((mrot & 1ull) ? 32 : 0);
    float amp = 0.f;
    #pragma unroll
    for (int j = 0; j < 8; ++j)
        amp = fmaf(st[j], tl[16 * (j >> 2) + 4 * q + (j & 3)], amp);
    amp += __shfl_xor(amp, 16);
    amp += __shfl_xor(amp, 32);

    if (l < 16)
        out[base + l] = logf(amp) + 0.69314718055994531f * (float)expsum;
}

extern "C" void kernel_launch(void* const* d_in, const int* in_sizes, int n_in,
                              void* d_out, int out_size, void* d_ws, size_t ws_size,
                              hipStream_t stream) {
    const float* t_first = (const float*)d_in[0];
    const float* t_mid   = (const float*)d_in[1];
    const float* t_last  = (const float*)d_in[2];
    const int*   x       = (const int*)d_in[3];
    float* out           = (float*)d_out;

    unsigned* wsP = (unsigned*)d_ws;  // 31 steps x 4KB (MX A-fragment rows) = 124 KB

    hipLaunchKernelGGL(prefix_kernel, dim3(NPAIR * 4), dim3(64), 0, stream, t_mid, wsP);
    hipLaunchKernelGGL(mps_mfma_kernel, dim3(BATCH / 64), dim3(256), 0, stream,
                       t_first, t_last, x, wsP, out);
}

// Round 2
// 80.304 us; speedup vs baseline: 1.0042x; 1.0042x over previous
//
#include <hip/hip_runtime.h>
#include <math.h>

#define NPAIR 31
#define BATCH 32768

typedef float f32x4 __attribute__((ext_vector_type(4)));
typedef int   i32x8 __attribute__((ext_vector_type(8)));
typedef unsigned int u32x2 __attribute__((ext_vector_type(2)));
typedef unsigned int u32x4 __attribute__((ext_vector_type(4)));

// pack 4 fp32 -> dword of 4 fp8 e4m3 (bytes 0..3 = a,b,c,d)
__device__ __forceinline__ unsigned pack_fp8x4(float a, float b, float c, float d) {
    int r = __builtin_amdgcn_cvt_pk_fp8_f32(a, b, 0, false);
    r = __builtin_amdgcn_cvt_pk_fp8_f32(c, d, r, true);
    return (unsigned)r;
}

// Pair swaps across 16-lane rows / 32-lane halves (gfx950 VALU permlane ops).
__device__ __forceinline__ void lane_swap16(unsigned a, unsigned& ev, unsigned& od) {
#if __has_builtin(__builtin_amdgcn_permlane16_swap)
    auto r = __builtin_amdgcn_permlane16_swap((int)a, (int)a, false, false);
    ev = (unsigned)r[0]; od = (unsigned)r[1];
#else
    unsigned p = (unsigned)__shfl_xor((int)a, 16);
    bool hi = (threadIdx.x >> 4) & 1;
    ev = hi ? p : a; od = hi ? a : p;
#endif
}
__device__ __forceinline__ void lane_swap32(unsigned a, unsigned& lo, unsigned& hi) {
#if __has_builtin(__builtin_amdgcn_permlane32_swap)
    auto r = __builtin_amdgcn_permlane32_swap((int)a, (int)a, false, false);
    lo = (unsigned)r[0]; hi = (unsigned)r[1];
#else
    unsigned p = (unsigned)__shfl_xor((int)a, 32);
    bool up = (threadIdx.x & 32) != 0;
    lo = up ? p : a; hi = up ? a : p;
#endif
}

// ---- Prefix: site-pair products T[2i][v0]*T[2i+1][v1] as fp8 MX-A rows -----
// Block = (pair i)*4 + variant v, lane (h,m).  o_t[j] = P[lam(8h+j)][16t+m].
// NEW ws layout (dwords): region r = 4*i + 2*t + c (c = chunk = h>>1), each
// region = 256 dwords = [64 lane-slots][16 B], lane-slot = v*16 + m.
// Main-kernel lane l then loads its 16 B chunk at r*256 + l*4 -> the wave's
// load is one contiguous 1 KB burst (fully coalesced), and chunk c holds
// A-bytes 16c..16c+15 in operand order.
__global__ __launch_bounds__(64) void prefix_kernel(const float* __restrict__ t_mid,
                                                    unsigned* __restrict__ wsP) {
    __shared__ float M1s[1024], M2s[1024];
    const int l = threadIdx.x, h = l >> 4, m = l & 15;
    const int i = blockIdx.x >> 2, v = blockIdx.x & 3;

    const float4* s1 = (const float4*)(t_mid + (size_t)((2 * i) * 2 + (v & 1)) * 1024);
    const float4* s2 = (const float4*)(t_mid + (size_t)((2 * i + 1) * 2 + (v >> 1)) * 1024);
    #pragma unroll
    for (int c = 0; c < 4; ++c) {
        ((float4*)M1s)[c * 64 + l] = s1[c * 64 + l];
        ((float4*)M2s)[c * 64 + l] = s2[c * 64 + l];
    }
    __syncthreads();

    // cache this lane's two output columns of M2
    float colv[2][32];
    #pragma unroll
    for (int t = 0; t < 2; ++t)
        #pragma unroll
        for (int mm = 0; mm < 32; ++mm)
            colv[t][mm] = M2s[mm * 32 + 16 * t + m];

    float o0[8], o1[8];  // tile0/tile1, byte j of this lane's h-block
    #pragma unroll
    for (int j = 0; j < 8; ++j) {
        int a = 16 * (j >> 2) + 4 * h + (j & 3);  // lam(8h+j)
        float acc0 = 0.f, acc1 = 0.f;
        #pragma unroll
        for (int mm = 0; mm < 32; ++mm) {
            float r = M1s[a * 32 + mm];
            acc0 = fmaf(r, colv[0][mm], acc0);
            acc1 = fmaf(r, colv[1][mm], acc1);
        }
        o0[j] = acc0;
        o1[j] = acc1;
    }

    const int slot4 = (v * 16 + m) * 4 + (h & 1) * 2;
    unsigned* dst0 = wsP + (size_t)(4 * i + (h >> 1)) * 256 + slot4;
    u32x2 w0 = {pack_fp8x4(o0[0], o0[1], o0[2], o0[3]),
                pack_fp8x4(o0[4], o0[5], o0[6], o0[7])};
    *(u32x2*)dst0 = w0;
    unsigned* dst1 = wsP + (size_t)(4 * i + 2 + (h >> 1)) * 256 + slot4;
    u32x2 w1 = {pack_fp8x4(o1[0], o1[1], o1[2], o1[3]),
                pack_fp8x4(o1[4], o1[5], o1[6], o1[7])};
    *(u32x2*)dst1 = w1;
}

// ---------------------------- Main MFMA kernel -----------------------------
// One wave = 16 batch elements (element = lane&15). Per step: gather the
// element's 32-component fp8 state across its 4 q-lanes (6 permlane swaps),
// mask to the variant K-block, ONE mfma_scale 16x16x128 per output tile.
// A-fragments live directly in i32x8 operand slots (4-slot rotation, fully
// unrolled loop -> compile-time indices, no per-step operand movs), loaded
// as 4 contiguous 1 KB bursts per step with prefetch distance 2.
__global__ __launch_bounds__(256, 2) void mps_mfma_kernel(
    const float* __restrict__ t_first,
    const float* __restrict__ t_last,
    const int*   __restrict__ x,
    const unsigned* __restrict__ wsP,
    float* __restrict__ out)
{
    const int tid  = threadIdx.x;
    const int w    = tid >> 6;
    const int l    = tid & 63;
    const int q    = l >> 4;
    const int e    = l & 15;
    const int base = (blockIdx.x * 4 + w) * 16;

    // ---- Inline spin mask for element e: bit s = (x[base+e][s] > 0). ----
    unsigned long long mrot;
    {
        const int4* xr = (const int4*)(x + (size_t)(base + e) * 64 + 16 * q);
        unsigned chunk = 0;
        #pragma unroll
        for (int c = 0; c < 4; ++c) {
            int4 vv = xr[c];
            chunk |= (unsigned)(vv.x > 0) << (4 * c + 0);
            chunk |= (unsigned)(vv.y > 0) << (4 * c + 1);
            chunk |= (unsigned)(vv.z > 0) << (4 * c + 2);
            chunk |= (unsigned)(vv.w > 0) << (4 * c + 3);
        }
        unsigned sh = chunk << ((q & 1) * 16);
        unsigned lo = (q < 2) ? sh : 0u;
        unsigned hi = (q >= 2) ? sh : 0u;
        lo |= (unsigned)__shfl_xor((int)lo, 16);
        lo |= (unsigned)__shfl_xor((int)lo, 32);
        hi |= (unsigned)__shfl_xor((int)hi, 16);
        hi |= (unsigned)__shfl_xor((int)hi, 32);
        unsigned long long mask = ((unsigned long long)hi << 32) | lo;
        // init below uses bit0; steps consume bits 1..62; bit63 = t_last
        mrot = mask >> 1;
    }

    // ---- Init state (lam component order) from t_first[bit0]. ----
    float st[8];
    {
        const float* tf = t_first + ((x[(size_t)(base + e) * 64] > 0) ? 32 : 0);
        #pragma unroll
        for (int j = 0; j < 8; ++j)
            st[j] = tf[16 * (j >> 2) + 4 * q + (j & 3)];
    }
    unsigned Bd0 = pack_fp8x4(st[0], st[1], st[2], st[3]);
    unsigned Bd1 = pack_fp8x4(st[4], st[5], st[6], st[7]);

    int expsum = 0;
    const f32x4 cz = {0.f, 0.f, 0.f, 0.f};

    // Step s, tile t, chunk c at u32x4 index (4s+2t+c)*64 + l (contiguous 1KB
    // per (t,c) across the wave).
    const u32x4* Wl = (const u32x4*)wsP + l;

    i32x8 Af0[4], Af1[4];  // [slot] -> A operand, tiles 0/1; slot = step & 3
#define LOADSLOT(sl, ss) do {                         \
        ((u32x4*)&Af0[sl])[0] = Wl[(4 * (ss) + 0) * 64]; \
        ((u32x4*)&Af0[sl])[1] = Wl[(4 * (ss) + 1) * 64]; \
        ((u32x4*)&Af1[sl])[0] = Wl[(4 * (ss) + 2) * 64]; \
        ((u32x4*)&Af1[sl])[1] = Wl[(4 * (ss) + 3) * 64]; \
    } while (0)

    LOADSLOT(0, 0);
    LOADSLOT(1, 1);

    #pragma unroll
    for (int s = 0; s < 31; ++s) {
        const int sl = s & 3;
        unsigned vl = (unsigned)mrot & 3u;
        mrot >>= 2;

        // gather full 32-component state into every lane (component order lam)
        unsigned E0, O0, E1, O1;
        lane_swap16(Bd0, E0, O0);
        lane_swap16(Bd1, E1, O1);
        unsigned g0, g1, g2, g3, g4, g5, g6, g7;
        lane_swap32(E0, g0, g4);
        lane_swap32(E1, g1, g5);
        lane_swap32(O0, g2, g6);
        lane_swap32(O1, g3, g7);

        const bool selq = (vl == (unsigned)q);
        i32x8 Bv;
        Bv[0] = selq ? (int)g0 : 0; Bv[1] = selq ? (int)g1 : 0;
        Bv[2] = selq ? (int)g2 : 0; Bv[3] = selq ? (int)g3 : 0;
        Bv[4] = selq ? (int)g4 : 0; Bv[5] = selq ? (int)g5 : 0;
        Bv[6] = selq ? (int)g6 : 0; Bv[7] = selq ? (int)g7 : 0;

        if (s < 29) {
            const int psl = (s + 2) & 3;
            LOADSLOT(psl, s + 2);
        }

        f32x4 y0 = __builtin_amdgcn_mfma_scale_f32_16x16x128_f8f6f4(
            Af0[sl], Bv, cz, 0, 0, 0, 0x7f7f7f7f, 0, 0x7f7f7f7f);
        f32x4 y1 = __builtin_amdgcn_mfma_scale_f32_16x16x128_f8f6f4(
            Af1[sl], Bv, cz, 0, 0, 0, 0x7f7f7f7f, 0, 0x7f7f7f7f);

        #pragma unroll
        for (int r = 0; r < 4; ++r) { st[r] = y0[r]; st[4 + r] = y1[r]; }

        // per-element pow2 rescale (uniform across the element's 4 q-lanes)
        float mx = fmaxf(fmaxf(fmaxf(st[0], st[1]), fmaxf(st[2], st[3])),
                         fmaxf(fmaxf(st[4], st[5]), fmaxf(st[6], st[7])));
        unsigned a_, b_;
        lane_swap16(__float_as_uint(mx), a_, b_);
        mx = fmaxf(__uint_as_float(a_), __uint_as_float(b_));
        lane_swap32(__float_as_uint(mx), a_, b_);
        mx = fmaxf(__uint_as_float(a_), __uint_as_float(b_));
        int ex = (int)((__float_as_uint(mx) >> 23) & 0xFF) - 127;
        float sc = __uint_as_float((unsigned)(127 - ex) << 23);
        #pragma unroll
        for (int j = 0; j < 8; ++j) st[j] *= sc;
        expsum += ex;

        Bd0 = pack_fp8x4(st[0], st[1], st[2], st[3]);
        Bd1 = pack_fp8x4(st[4], st[5], st[6], st[7]);
    }
#undef LOADSLOT

    // ---- Epilogue: amp = dot(state, t_last[bit63]); reduce over q. ----
    const float* tl = t_last + ((mrot & 1ull) ? 32 : 0);
    float amp = 0.f;
    #pragma unroll
    for (int j = 0; j < 8; ++j)
        amp = fmaf(st[j], tl[16 * (j >> 2) + 4 * q + (j & 3)], amp);
    amp += __shfl_xor(amp, 16);
    amp += __shfl_xor(amp, 32);

    if (l < 16)
        out[base + l] = logf(amp) + 0.69314718055994531f * (float)expsum;
}

extern "C" void kernel_launch(void* const* d_in, const int* in_sizes, int n_in,
                              void* d_out, int out_size, void* d_ws, size_t ws_size,
                              hipStream_t stream) {
    const float* t_first = (const float*)d_in[0];
    const float* t_mid   = (const float*)d_in[1];
    const float* t_last  = (const float*)d_in[2];
    const int*   x       = (const int*)d_in[3];
    float* out           = (float*)d_out;

    unsigned* wsP = (unsigned*)d_ws;  // 124 regions x 1 KB = 124 KB

    hipLaunchKernelGGL(prefix_kernel, dim3(NPAIR * 4), dim3(64), 0, stream, t_mid, wsP);
    hipLaunchKernelGGL(mps_mfma_kernel, dim3(BATCH / 64), dim3(256), 0, stream,
                       t_first, t_last, x, wsP, out);
}